// Round 9
// baseline (399.517 us; speedup 1.0000x reference)
//
#include <hip/hip_runtime.h>

#define N_EDGES 1600000
#define N_NODES 50000
#define D_FEAT  32

#define BSHIFT  6
#define NPB     64                                   // nodes per bucket
#define NB      ((N_NODES + NPB - 1) / NPB)          // 782 buckets
#define CHUNK   4096                                 // edges per partition block
#define NBLK    ((N_EDGES + CHUNK - 1) / CHUNK)      // 391 blocks
#define EPT     (CHUNK / 256)                        // 16 edges/thread

// ---- workspace layout (bytes) ----
#define BLKCNT_OFF 0                                                      // int[NBLK*NB]
#define START_OFF  ((((size_t)NBLK * NB * 4 + 255) / 256) * 256)          // int[NB+1]
#define ENT_OFF    (START_OFF + ((((size_t)(NB + 1) * 4 + 255) / 256) * 256))  // int2[N_EDGES]
#define WS_NEEDED  (ENT_OFF + (size_t)N_EDGES * 8)

// P1: per-block bucket histogram (LDS int atomics, zero global atomics).
__global__ __launch_bounds__(256) void count_kernel(const int* __restrict__ index,
                                                    int* __restrict__ blockcnt) {
    __shared__ int lcnt[NB];
    int t = threadIdx.x;
    for (int k = t; k < NB; k += 256) lcnt[k] = 0;
    __syncthreads();
    int base = blockIdx.x * CHUNK;
    #pragma unroll
    for (int j = 0; j < EPT; ++j) {
        int e = base + j * 256 + t;
        if (e < N_EDGES) atomicAdd(&lcnt[index[e] >> BSHIFT], 1);
    }
    __syncthreads();
    for (int k = t; k < NB; k += 256)
        blockcnt[(size_t)blockIdx.x * NB + k] = lcnt[k];
}

// P2: single block. Column-scan blockcnt (prefix per bucket across blocks,
// in place) + exclusive scan of bucket totals -> startg[NB+1].
__global__ __launch_bounds__(1024) void scan_kernel(int* __restrict__ blockcnt,
                                                    int* __restrict__ startg) {
    __shared__ int part[1024];
    int t = threadIdx.x;
    int tot = 0;
    if (t < NB) {
        int run = 0;
        for (int b = 0; b < NBLK; ++b) {
            int v = blockcnt[(size_t)b * NB + t];
            blockcnt[(size_t)b * NB + t] = run;   // per-block base within bucket
            run += v;
        }
        tot = run;
    }
    part[t] = tot;
    __syncthreads();
    int inc = tot;
    for (int d = 1; d < 1024; d <<= 1) {
        int w = (t >= d) ? part[t - d] : 0;
        __syncthreads();
        inc += w;
        part[t] = inc;
        __syncthreads();
    }
    if (t < NB) startg[t] = inc - tot;
    if (t == NB - 1) startg[NB] = inc;            // = N_EDGES
}

// P3: block-local multisplit. LDS rank -> LDS scan -> bucket-ordered staging
// -> segment-coalesced global writes of int2{node, edge}.
__global__ __launch_bounds__(256) void partition_kernel(const int* __restrict__ index,
                                                        const int* __restrict__ blockcnt,
                                                        const int* __restrict__ startg,
                                                        int2* __restrict__ entries) {
    __shared__ int lcnt[NB];
    __shared__ int loff[NB];
    __shared__ int lbase[NB];
    __shared__ int scanp[256];
    __shared__ int2 stage[CHUNK];                  // 32 KB
    int t = threadIdx.x;
    int b = blockIdx.x;
    for (int k = t; k < NB; k += 256) lcnt[k] = 0;
    __syncthreads();
    int base = b * CHUNK;
    int nd[EPT], rk[EPT];
    #pragma unroll
    for (int j = 0; j < EPT; ++j) {
        int e = base + j * 256 + t;
        nd[j] = -1;
        if (e < N_EDGES) {
            nd[j] = index[e];
            rk[j] = atomicAdd(&lcnt[nd[j] >> BSHIFT], 1);
        }
    }
    __syncthreads();
    // exclusive scan of lcnt[0..NB) with 256 threads (C=4 chunks/thread)
    {
        const int C = (NB + 255) / 256;            // 4
        int mybase = t * C;
        int s = 0;
        #pragma unroll
        for (int j = 0; j < C; ++j) {
            int i = mybase + j;
            if (i < NB) s += lcnt[i];
        }
        scanp[t] = s;
        __syncthreads();
        int inc = s;
        for (int d = 1; d < 256; d <<= 1) {
            int w = (t >= d) ? scanp[t - d] : 0;
            __syncthreads();
            inc += w;
            scanp[t] = inc;
            __syncthreads();
        }
        int run = inc - s;
        #pragma unroll
        for (int j = 0; j < C; ++j) {
            int i = mybase + j;
            if (i < NB) { loff[i] = run; run += lcnt[i]; }
        }
    }
    for (int k = t; k < NB; k += 256)
        lbase[k] = startg[k] + blockcnt[(size_t)b * NB + k];
    __syncthreads();
    #pragma unroll
    for (int j = 0; j < EPT; ++j) {
        if (nd[j] >= 0) {
            int e = base + j * 256 + t;
            int k = nd[j] >> BSHIFT;
            stage[loff[k] + rk[j]] = make_int2(nd[j], e);
        }
    }
    __syncthreads();
    int total = loff[NB - 1] + lcnt[NB - 1];
    for (int i = t; i < total; i += 256) {
        int2 ent = stage[i];
        int k = ent.x >> BSHIFT;
        entries[lbase[k] + (i - loff[k])] = ent;   // consecutive i -> consecutive gpos
    }
}

// P4: one block per bucket. 8KB LDS tile, ds_add_f32 accumulate, src rows
// read as coalesced 128B, out written once coalesced (with out_in added).
__global__ __launch_bounds__(512) void bucket_gather_kernel(const float* __restrict__ src,
                                                            const int2* __restrict__ entries,
                                                            const int* __restrict__ startg,
                                                            const float4* __restrict__ out_in4,
                                                            float4* __restrict__ out4) {
    __shared__ float tile[NPB * D_FEAT];           // 8 KB
    int t = threadIdx.x;
    int k = blockIdx.x;
    for (int i = t; i < NPB * D_FEAT; i += 512) tile[i] = 0.f;
    __syncthreads();
    int s0 = startg[k], s1 = startg[k + 1];
    int slot = t >> 5;                             // 0..15
    int f = t & 31;
    int i = s0 + slot;
    for (; i + 48 < s1; i += 64) {                 // 4 independent rows/thread-step
        int2 e0 = entries[i];
        int2 e1 = entries[i + 16];
        int2 e2 = entries[i + 32];
        int2 e3 = entries[i + 48];
        float v0 = src[(size_t)e0.y * D_FEAT + f];
        float v1 = src[(size_t)e1.y * D_FEAT + f];
        float v2 = src[(size_t)e2.y * D_FEAT + f];
        float v3 = src[(size_t)e3.y * D_FEAT + f];
        atomicAdd(&tile[(e0.x & (NPB - 1)) * D_FEAT + f], v0);
        atomicAdd(&tile[(e1.x & (NPB - 1)) * D_FEAT + f], v1);
        atomicAdd(&tile[(e2.x & (NPB - 1)) * D_FEAT + f], v2);
        atomicAdd(&tile[(e3.x & (NPB - 1)) * D_FEAT + f], v3);
    }
    for (; i < s1; i += 16) {
        int2 e0 = entries[i];
        float v0 = src[(size_t)e0.y * D_FEAT + f];
        atomicAdd(&tile[(e0.x & (NPB - 1)) * D_FEAT + f], v0);
    }
    __syncthreads();
    // 512 threads -> 512 float4 = 64 nodes x 32 feats
    int n = t >> 3, f4 = t & 7;
    int gnode = k * NPB + n;
    if (gnode < N_NODES) {
        const float4* tp = (const float4*)tile;
        float4 acc = tp[t];
        size_t o = (size_t)gnode * 8 + f4;
        float4 bo = out_in4[o];
        bo.x += acc.x; bo.y += acc.y; bo.z += acc.z; bo.w += acc.w;
        out4[o] = bo;
    }
}

// ---- fallback: round-8 proven direct atomic path ----
__global__ void init_out_kernel(const float4* __restrict__ out_in,
                                float4* __restrict__ out, int n4) {
    int i = blockIdx.x * blockDim.x + threadIdx.x;
    int stride = gridDim.x * blockDim.x;
    for (; i < n4; i += stride) out[i] = out_in[i];
}
__global__ void scatter_direct_kernel(const float* __restrict__ src,
                                      const int* __restrict__ index,
                                      float* __restrict__ out) {
    const long total = (long)N_EDGES * D_FEAT;
    long i = (long)blockIdx.x * blockDim.x + threadIdx.x;
    const long stride = (long)gridDim.x * blockDim.x;
    for (; i < total; i += stride) {
        int e = (int)(i >> 5);
        int f = (int)(i & 31);
        float v = src[i];
        int node = index[e];
        atomicAdd(&out[(size_t)node * D_FEAT + f], v);
    }
}

extern "C" void kernel_launch(void* const* d_in, const int* in_sizes, int n_in,
                              void* d_out, int out_size, void* d_ws, size_t ws_size,
                              hipStream_t stream) {
    const float* src    = (const float*)d_in[0];
    const int*   index  = (const int*)d_in[1];
    const float* out_in = (const float*)d_in[2];
    float* out          = (float*)d_out;

    if (ws_size < WS_NEEDED) {
        int n4 = out_size / 4;
        init_out_kernel<<<1563, 256, 0, stream>>>((const float4*)out_in, (float4*)out, n4);
        scatter_direct_kernel<<<2048, 256, 0, stream>>>(src, index, out);
        return;
    }

    char* ws = (char*)d_ws;
    int*  blockcnt = (int*)(ws + BLKCNT_OFF);
    int*  startg   = (int*)(ws + START_OFF);
    int2* entries  = (int2*)(ws + ENT_OFF);

    count_kernel<<<NBLK, 256, 0, stream>>>(index, blockcnt);
    scan_kernel<<<1, 1024, 0, stream>>>(blockcnt, startg);
    partition_kernel<<<NBLK, 256, 0, stream>>>(index, blockcnt, startg, entries);
    bucket_gather_kernel<<<NB, 512, 0, stream>>>(src, entries, startg,
                                                 (const float4*)out_in, (float4*)out);
}

// Round 10
// 127.001 us; speedup vs baseline: 3.1458x; 3.1458x over previous
//
#include <hip/hip_runtime.h>

#define N_EDGES 1600000
#define N_NODES 50000
#define D_FEAT  32

#define BSHIFT  6
#define NPB     64                                   // nodes per bucket
#define NB      ((N_NODES + NPB - 1) / NPB)          // 782 buckets
#define CHUNK   4096                                 // edges per partition block
#define NBLK    ((N_EDGES + CHUNK - 1) / CHUNK)      // 391 blocks
#define EPT     (CHUNK / 256)                        // 16 edges/thread

// ---- workspace layout (bytes) ----
#define BLKCNT_OFF 0                                                       // int[NBLK*NB]
#define START_OFF  ((((size_t)NBLK * NB * 4 + 255) / 256) * 256)           // int[NB+1]
#define PB_OFF     (START_OFF + ((((size_t)(NB + 1) * 4 + 255) / 256) * 256)) // int[N_EDGES]
#define OFFS_OFF   (PB_OFF + (size_t)N_EDGES * 4)                          // int[N_NODES+1]
#define PERM_OFF   (OFFS_OFF + ((((size_t)(N_NODES + 1) * 4 + 255) / 256) * 256)) // int[N_EDGES]
#define WS_NEEDED  (PERM_OFF + (size_t)N_EDGES * 4)

// P1: per-block bucket histogram (LDS atomics only).
__global__ __launch_bounds__(256) void count_kernel(const int* __restrict__ index,
                                                    int* __restrict__ blockcnt) {
    __shared__ int lcnt[NB];
    int t = threadIdx.x;
    for (int k = t; k < NB; k += 256) lcnt[k] = 0;
    __syncthreads();
    int base = blockIdx.x * CHUNK;
    #pragma unroll
    for (int j = 0; j < EPT; ++j) {
        int e = base + j * 256 + t;
        if (e < N_EDGES) atomicAdd(&lcnt[index[e] >> BSHIFT], 1);
    }
    __syncthreads();
    for (int k = t; k < NB; k += 256)
        blockcnt[(size_t)blockIdx.x * NB + k] = lcnt[k];
}

// P2: column-scan blockcnt + exclusive scan of bucket totals -> startg.
__global__ __launch_bounds__(1024) void scan_kernel(int* __restrict__ blockcnt,
                                                    int* __restrict__ startg) {
    __shared__ int part[1024];
    int t = threadIdx.x;
    int tot = 0;
    if (t < NB) {
        int run = 0;
        for (int b = 0; b < NBLK; ++b) {
            int v = blockcnt[(size_t)b * NB + t];
            blockcnt[(size_t)b * NB + t] = run;
            run += v;
        }
        tot = run;
    }
    part[t] = tot;
    __syncthreads();
    int inc = tot;
    for (int d = 1; d < 1024; d <<= 1) {
        int w = (t >= d) ? part[t - d] : 0;
        __syncthreads();
        inc += w;
        part[t] = inc;
        __syncthreads();
    }
    if (t < NB) startg[t] = inc - tot;
    if (t == NB - 1) startg[NB] = inc;
}

// P3: block-local multisplit -> bucket-ordered edge ids (coalesced writes).
__global__ __launch_bounds__(256) void partition_kernel(const int* __restrict__ index,
                                                        const int* __restrict__ blockcnt,
                                                        const int* __restrict__ startg,
                                                        int* __restrict__ pb) {
    __shared__ int lcnt[NB];
    __shared__ int loff[NB];
    __shared__ int lbase[NB];
    __shared__ int scanp[256];
    __shared__ int2 stage[CHUNK];                  // 32 KB (node, edge)
    int t = threadIdx.x;
    int b = blockIdx.x;
    for (int k = t; k < NB; k += 256) lcnt[k] = 0;
    __syncthreads();
    int base = b * CHUNK;
    int nd[EPT], rk[EPT];
    #pragma unroll
    for (int j = 0; j < EPT; ++j) {
        int e = base + j * 256 + t;
        nd[j] = -1;
        if (e < N_EDGES) {
            nd[j] = index[e];
            rk[j] = atomicAdd(&lcnt[nd[j] >> BSHIFT], 1);
        }
    }
    __syncthreads();
    {   // exclusive scan of lcnt[0..NB)
        const int C = (NB + 255) / 256;            // 4
        int mybase = t * C;
        int s = 0;
        #pragma unroll
        for (int j = 0; j < C; ++j) {
            int i = mybase + j;
            if (i < NB) s += lcnt[i];
        }
        scanp[t] = s;
        __syncthreads();
        int inc = s;
        for (int d = 1; d < 256; d <<= 1) {
            int w = (t >= d) ? scanp[t - d] : 0;
            __syncthreads();
            inc += w;
            scanp[t] = inc;
            __syncthreads();
        }
        int run = inc - s;
        #pragma unroll
        for (int j = 0; j < C; ++j) {
            int i = mybase + j;
            if (i < NB) { loff[i] = run; run += lcnt[i]; }
        }
    }
    for (int k = t; k < NB; k += 256)
        lbase[k] = startg[k] + blockcnt[(size_t)b * NB + k];
    __syncthreads();
    #pragma unroll
    for (int j = 0; j < EPT; ++j) {
        if (nd[j] >= 0) {
            int e = base + j * 256 + t;
            int k = nd[j] >> BSHIFT;
            stage[loff[k] + rk[j]] = make_int2(nd[j], e);
        }
    }
    __syncthreads();
    int total = loff[NB - 1] + lcnt[NB - 1];
    for (int i = t; i < total; i += 256) {
        int2 ent = stage[i];
        int k = ent.x >> BSHIFT;
        pb[lbase[k] + (i - loff[k])] = ent.y;      // coalesced per segment
    }
}

// P4: per-bucket local CSR -> node-sorted perm + global offs. All edges of a
// bucket's nodes are in [startg[k], startg[k+1]), so per-node offsets are
// fully determined locally. Two L2-hot passes over ~2046 ids.
__global__ __launch_bounds__(256) void finish_kernel(const int* __restrict__ pb,
                                                     const int* __restrict__ index,
                                                     const int* __restrict__ startg,
                                                     int* __restrict__ offs,
                                                     int* __restrict__ perm) {
    __shared__ int lcnt[NPB];
    __shared__ int lcur[NPB];
    int t = threadIdx.x;
    int k = blockIdx.x;
    if (t < NPB) lcnt[t] = 0;
    __syncthreads();
    int s0 = startg[k], s1 = startg[k + 1];
    for (int i = s0 + t; i < s1; i += 256)
        atomicAdd(&lcnt[index[pb[i]] & (NPB - 1)], 1);
    __syncthreads();
    if (t == 0) {
        int run = 0;
        for (int n = 0; n < NPB; ++n) {
            int c = lcnt[n];
            lcnt[n] = run;
            lcur[n] = run;
            run += c;
        }
    }
    __syncthreads();
    if (t < NPB) {
        int gnode = k * NPB + t;
        if (gnode < N_NODES) offs[gnode] = s0 + lcnt[t];
    }
    if (k == 0 && t == 64) offs[N_NODES] = N_EDGES;
    for (int i = s0 + t; i < s1; i += 256) {
        int eid = pb[i];
        int n = index[eid] & (NPB - 1);
        int r = atomicAdd(&lcur[n], 1);
        perm[s0 + r] = eid;                        // scattered within 8KB window
    }
}

// P5: PROVEN r5/r6 gather. One wave/node; lane = slot*8 + f4; 4-deep unroll
// -> 32 independent 128B rows (4KB) in flight per wave; 12500 blocks.
__global__ void gather_sum_kernel(const float4* __restrict__ src4,
                                  const int* __restrict__ perm,
                                  const int* __restrict__ offs,
                                  const float4* __restrict__ out_in4,
                                  float4* __restrict__ out4) {
    int wave = threadIdx.x >> 6;
    int node = blockIdx.x * 4 + wave;
    if (node >= N_NODES) return;
    int lane = threadIdx.x & 63;
    int slot = lane >> 3;
    int f4   = lane & 7;
    int start = offs[node];
    int end   = offs[node + 1];

    float4 a0 = {0,0,0,0}, a1 = {0,0,0,0}, a2 = {0,0,0,0}, a3 = {0,0,0,0};
    int i = start + slot;
    for (; i + 24 < end; i += 32) {
        int e0 = perm[i];
        int e1 = perm[i + 8];
        int e2 = perm[i + 16];
        int e3 = perm[i + 24];
        float4 v0 = src4[(size_t)e0 * 8 + f4];
        float4 v1 = src4[(size_t)e1 * 8 + f4];
        float4 v2 = src4[(size_t)e2 * 8 + f4];
        float4 v3 = src4[(size_t)e3 * 8 + f4];
        a0.x += v0.x; a0.y += v0.y; a0.z += v0.z; a0.w += v0.w;
        a1.x += v1.x; a1.y += v1.y; a1.z += v1.z; a1.w += v1.w;
        a2.x += v2.x; a2.y += v2.y; a2.z += v2.z; a2.w += v2.w;
        a3.x += v3.x; a3.y += v3.y; a3.z += v3.z; a3.w += v3.w;
    }
    for (; i < end; i += 8) {
        int e0 = perm[i];
        float4 v0 = src4[(size_t)e0 * 8 + f4];
        a0.x += v0.x; a0.y += v0.y; a0.z += v0.z; a0.w += v0.w;
    }
    a0.x += a1.x + a2.x + a3.x;
    a0.y += a1.y + a2.y + a3.y;
    a0.z += a1.z + a2.z + a3.z;
    a0.w += a1.w + a2.w + a3.w;

    for (int m = 8; m <= 32; m <<= 1) {
        a0.x += __shfl_xor(a0.x, m, 64);
        a0.y += __shfl_xor(a0.y, m, 64);
        a0.z += __shfl_xor(a0.z, m, 64);
        a0.w += __shfl_xor(a0.w, m, 64);
    }
    if (slot == 0) {
        size_t o = (size_t)node * 8 + f4;
        float4 b = out_in4[o];
        b.x += a0.x; b.y += a0.y; b.z += a0.z; b.w += a0.w;
        out4[o] = b;
    }
}

// ---- fallback: round-8 proven direct atomic path (171 us) ----
__global__ void init_out_kernel(const float4* __restrict__ out_in,
                                float4* __restrict__ out, int n4) {
    int i = blockIdx.x * blockDim.x + threadIdx.x;
    int stride = gridDim.x * blockDim.x;
    for (; i < n4; i += stride) out[i] = out_in[i];
}
__global__ void scatter_direct_kernel(const float* __restrict__ src,
                                      const int* __restrict__ index,
                                      float* __restrict__ out) {
    const long total = (long)N_EDGES * D_FEAT;
    long i = (long)blockIdx.x * blockDim.x + threadIdx.x;
    const long stride = (long)gridDim.x * blockDim.x;
    for (; i < total; i += stride) {
        int e = (int)(i >> 5);
        int f = (int)(i & 31);
        float v = src[i];
        int node = index[e];
        atomicAdd(&out[(size_t)node * D_FEAT + f], v);
    }
}

extern "C" void kernel_launch(void* const* d_in, const int* in_sizes, int n_in,
                              void* d_out, int out_size, void* d_ws, size_t ws_size,
                              hipStream_t stream) {
    const float* src    = (const float*)d_in[0];
    const int*   index  = (const int*)d_in[1];
    const float* out_in = (const float*)d_in[2];
    float* out          = (float*)d_out;

    if (ws_size < WS_NEEDED) {
        int n4 = out_size / 4;
        init_out_kernel<<<1563, 256, 0, stream>>>((const float4*)out_in, (float4*)out, n4);
        scatter_direct_kernel<<<2048, 256, 0, stream>>>(src, index, out);
        return;
    }

    char* ws = (char*)d_ws;
    int* blockcnt = (int*)(ws + BLKCNT_OFF);
    int* startg   = (int*)(ws + START_OFF);
    int* pb       = (int*)(ws + PB_OFF);
    int* offs     = (int*)(ws + OFFS_OFF);
    int* perm     = (int*)(ws + PERM_OFF);

    count_kernel<<<NBLK, 256, 0, stream>>>(index, blockcnt);
    scan_kernel<<<1, 1024, 0, stream>>>(blockcnt, startg);
    partition_kernel<<<NBLK, 256, 0, stream>>>(index, blockcnt, startg, pb);
    finish_kernel<<<NB, 256, 0, stream>>>(pb, index, startg, offs, perm);
    gather_sum_kernel<<<(N_NODES + 3) / 4, 256, 0, stream>>>(
        (const float4*)src, perm, offs, (const float4*)out_in, (float4*)out);
}

// Round 11
// 79.618 us; speedup vs baseline: 5.0179x; 1.5951x over previous
//
#include <hip/hip_runtime.h>

#define N_EDGES 1600000
#define N_NODES 50000
#define D_FEAT  32

#define BSHIFT  6
#define NPB     64                                   // nodes per bucket
#define NB      ((N_NODES + NPB - 1) / NPB)          // 782 buckets
#define CHUNK   4096                                 // edges per partition block
#define NBLK    ((N_EDGES + CHUNK - 1) / CHUNK)      // 391 blocks
#define EPT     (CHUNK / 256)                        // 16 edges/thread

// ---- workspace layout (bytes) ----
#define BLKCNT_OFF 0                                                       // int[NBLK*NB]
#define START_OFF  ((((size_t)NBLK * NB * 4 + 255) / 256) * 256)           // int[NB+1]
#define PB_OFF     (START_OFF + ((((size_t)(NB + 1) * 4 + 255) / 256) * 256)) // int[N_EDGES]
#define OFFS_OFF   (PB_OFF + (size_t)N_EDGES * 4)                          // int[N_NODES+1]
#define PERM_OFF   (OFFS_OFF + ((((size_t)(N_NODES + 1) * 4 + 255) / 256) * 256)) // int[N_EDGES]
#define WS_NEEDED  (PERM_OFF + (size_t)N_EDGES * 4)

// P1: per-block bucket histogram (LDS atomics only).
__global__ __launch_bounds__(256) void count_kernel(const int* __restrict__ index,
                                                    int* __restrict__ blockcnt) {
    __shared__ int lcnt[NB];
    int t = threadIdx.x;
    for (int k = t; k < NB; k += 256) lcnt[k] = 0;
    __syncthreads();
    int base = blockIdx.x * CHUNK;
    #pragma unroll
    for (int j = 0; j < EPT; ++j) {
        int e = base + j * 256 + t;
        if (e < N_EDGES) atomicAdd(&lcnt[index[e] >> BSHIFT], 1);
    }
    __syncthreads();
    for (int k = t; k < NB; k += 256)
        blockcnt[(size_t)blockIdx.x * NB + k] = lcnt[k];
}

// P2a: PARALLEL column scan — one wave per bucket, shfl prefix over the 391
// per-block counts (L2-resident). Replaces the single-block serial walk.
// blockcnt becomes exclusive-prefix-within-bucket; startg[k] = bucket total.
__global__ __launch_bounds__(256) void scan_col_kernel(int* __restrict__ blockcnt,
                                                       int* __restrict__ startg) {
    int wid  = (blockIdx.x * 256 + threadIdx.x) >> 6;
    int lane = threadIdx.x & 63;
    if (wid >= NB) return;
    int carry = 0;
    const int CH = (NBLK + 63) / 64;                 // 7 chunks
    for (int c = 0; c < CH; ++c) {
        int b = c * 64 + lane;
        int v = (b < NBLK) ? blockcnt[(size_t)b * NB + wid] : 0;
        int incl = v;
        #pragma unroll
        for (int d = 1; d < 64; d <<= 1) {
            int up = __shfl_up(incl, d, 64);
            if (lane >= d) incl += up;
        }
        if (b < NBLK) blockcnt[(size_t)b * NB + wid] = carry + incl - v;
        carry += __shfl(incl, 63, 64);
    }
    if (lane == 0) startg[wid] = carry;
}

// P2b: single-block exclusive scan of the 782 bucket totals (in place).
__global__ __launch_bounds__(1024) void scan_bucket_kernel(int* __restrict__ startg) {
    __shared__ int part[1024];
    int t = threadIdx.x;
    int v = (t < NB) ? startg[t] : 0;
    part[t] = v;
    __syncthreads();
    int inc = v;
    for (int d = 1; d < 1024; d <<= 1) {
        int w = (t >= d) ? part[t - d] : 0;
        __syncthreads();
        inc += w;
        part[t] = inc;
        __syncthreads();
    }
    if (t < NB) startg[t] = inc - v;
    if (t == 0) startg[NB] = N_EDGES;
}

// P3: block-local multisplit -> bucket-ordered PACKED entries
// pb[i] = (edge<<6) | (node&63)  (edge < 2^21, fits 27 bits).
__global__ __launch_bounds__(256) void partition_kernel(const int* __restrict__ index,
                                                        const int* __restrict__ blockcnt,
                                                        const int* __restrict__ startg,
                                                        int* __restrict__ pb) {
    __shared__ int lcnt[NB];
    __shared__ int loff[NB];
    __shared__ int lbase[NB];
    __shared__ int scanp[256];
    __shared__ int2 stage[CHUNK];                  // 32 KB (node, edge)
    int t = threadIdx.x;
    int b = blockIdx.x;
    for (int k = t; k < NB; k += 256) lcnt[k] = 0;
    __syncthreads();
    int base = b * CHUNK;
    int nd[EPT], rk[EPT];
    #pragma unroll
    for (int j = 0; j < EPT; ++j) {
        int e = base + j * 256 + t;
        nd[j] = -1;
        if (e < N_EDGES) {
            nd[j] = index[e];
            rk[j] = atomicAdd(&lcnt[nd[j] >> BSHIFT], 1);
        }
    }
    __syncthreads();
    {   // exclusive scan of lcnt[0..NB)
        const int C = (NB + 255) / 256;            // 4
        int mybase = t * C;
        int s = 0;
        #pragma unroll
        for (int j = 0; j < C; ++j) {
            int i = mybase + j;
            if (i < NB) s += lcnt[i];
        }
        scanp[t] = s;
        __syncthreads();
        int inc = s;
        for (int d = 1; d < 256; d <<= 1) {
            int w = (t >= d) ? scanp[t - d] : 0;
            __syncthreads();
            inc += w;
            scanp[t] = inc;
            __syncthreads();
        }
        int run = inc - s;
        #pragma unroll
        for (int j = 0; j < C; ++j) {
            int i = mybase + j;
            if (i < NB) { loff[i] = run; run += lcnt[i]; }
        }
    }
    for (int k = t; k < NB; k += 256)
        lbase[k] = startg[k] + blockcnt[(size_t)b * NB + k];
    __syncthreads();
    #pragma unroll
    for (int j = 0; j < EPT; ++j) {
        if (nd[j] >= 0) {
            int e = base + j * 256 + t;
            int k = nd[j] >> BSHIFT;
            stage[loff[k] + rk[j]] = make_int2(nd[j], e);
        }
    }
    __syncthreads();
    int total = loff[NB - 1] + lcnt[NB - 1];
    for (int i = t; i < total; i += 256) {
        int2 ent = stage[i];
        int k = ent.x >> BSHIFT;
        pb[lbase[k] + (i - loff[k])] = (ent.y << BSHIFT) | (ent.x & (NPB - 1));
    }
}

// P4: per-bucket local CSR from PACKED entries (no index re-read) ->
// node-sorted perm (pure edge ids) + global offs.
__global__ __launch_bounds__(256) void finish_kernel(const int* __restrict__ pb,
                                                     const int* __restrict__ startg,
                                                     int* __restrict__ offs,
                                                     int* __restrict__ perm) {
    __shared__ int lcnt[NPB];
    __shared__ int lcur[NPB];
    int t = threadIdx.x;
    int k = blockIdx.x;
    if (t < NPB) lcnt[t] = 0;
    __syncthreads();
    int s0 = startg[k], s1 = startg[k + 1];
    for (int i = s0 + t; i < s1; i += 256)
        atomicAdd(&lcnt[pb[i] & (NPB - 1)], 1);
    __syncthreads();
    if (t == 0) {
        int run = 0;
        for (int n = 0; n < NPB; ++n) {
            int c = lcnt[n];
            lcnt[n] = run;
            lcur[n] = run;
            run += c;
        }
    }
    __syncthreads();
    if (t < NPB) {
        int gnode = k * NPB + t;
        if (gnode < N_NODES) offs[gnode] = s0 + lcnt[t];
    }
    if (k == 0 && t == 64) offs[N_NODES] = N_EDGES;
    for (int i = s0 + t; i < s1; i += 256) {
        int pv = pb[i];
        int n = pv & (NPB - 1);
        int r = atomicAdd(&lcur[n], 1);
        perm[s0 + r] = pv >> BSHIFT;               // pure edge id
    }
}

// P5: proven gather. One wave/node; lane = slot*8 + f4; 4-deep unroll.
__global__ void gather_sum_kernel(const float4* __restrict__ src4,
                                  const int* __restrict__ perm,
                                  const int* __restrict__ offs,
                                  const float4* __restrict__ out_in4,
                                  float4* __restrict__ out4) {
    int wave = threadIdx.x >> 6;
    int node = blockIdx.x * 4 + wave;
    if (node >= N_NODES) return;
    int lane = threadIdx.x & 63;
    int slot = lane >> 3;
    int f4   = lane & 7;
    int start = offs[node];
    int end   = offs[node + 1];

    float4 a0 = {0,0,0,0}, a1 = {0,0,0,0}, a2 = {0,0,0,0}, a3 = {0,0,0,0};
    int i = start + slot;
    for (; i + 24 < end; i += 32) {
        int e0 = perm[i];
        int e1 = perm[i + 8];
        int e2 = perm[i + 16];
        int e3 = perm[i + 24];
        float4 v0 = src4[(size_t)e0 * 8 + f4];
        float4 v1 = src4[(size_t)e1 * 8 + f4];
        float4 v2 = src4[(size_t)e2 * 8 + f4];
        float4 v3 = src4[(size_t)e3 * 8 + f4];
        a0.x += v0.x; a0.y += v0.y; a0.z += v0.z; a0.w += v0.w;
        a1.x += v1.x; a1.y += v1.y; a1.z += v1.z; a1.w += v1.w;
        a2.x += v2.x; a2.y += v2.y; a2.z += v2.z; a2.w += v2.w;
        a3.x += v3.x; a3.y += v3.y; a3.z += v3.z; a3.w += v3.w;
    }
    for (; i < end; i += 8) {
        int e0 = perm[i];
        float4 v0 = src4[(size_t)e0 * 8 + f4];
        a0.x += v0.x; a0.y += v0.y; a0.z += v0.z; a0.w += v0.w;
    }
    a0.x += a1.x + a2.x + a3.x;
    a0.y += a1.y + a2.y + a3.y;
    a0.z += a1.z + a2.z + a3.z;
    a0.w += a1.w + a2.w + a3.w;

    for (int m = 8; m <= 32; m <<= 1) {
        a0.x += __shfl_xor(a0.x, m, 64);
        a0.y += __shfl_xor(a0.y, m, 64);
        a0.z += __shfl_xor(a0.z, m, 64);
        a0.w += __shfl_xor(a0.w, m, 64);
    }
    if (slot == 0) {
        size_t o = (size_t)node * 8 + f4;
        float4 b = out_in4[o];
        b.x += a0.x; b.y += a0.y; b.z += a0.z; b.w += a0.w;
        out4[o] = b;
    }
}

// ---- fallback: round-8 proven direct atomic path (171 us) ----
__global__ void init_out_kernel(const float4* __restrict__ out_in,
                                float4* __restrict__ out, int n4) {
    int i = blockIdx.x * blockDim.x + threadIdx.x;
    int stride = gridDim.x * blockDim.x;
    for (; i < n4; i += stride) out[i] = out_in[i];
}
__global__ void scatter_direct_kernel(const float* __restrict__ src,
                                      const int* __restrict__ index,
                                      float* __restrict__ out) {
    const long total = (long)N_EDGES * D_FEAT;
    long i = (long)blockIdx.x * blockDim.x + threadIdx.x;
    const long stride = (long)gridDim.x * blockDim.x;
    for (; i < total; i += stride) {
        int e = (int)(i >> 5);
        int f = (int)(i & 31);
        float v = src[i];
        int node = index[e];
        atomicAdd(&out[(size_t)node * D_FEAT + f], v);
    }
}

extern "C" void kernel_launch(void* const* d_in, const int* in_sizes, int n_in,
                              void* d_out, int out_size, void* d_ws, size_t ws_size,
                              hipStream_t stream) {
    const float* src    = (const float*)d_in[0];
    const int*   index  = (const int*)d_in[1];
    const float* out_in = (const float*)d_in[2];
    float* out          = (float*)d_out;

    if (ws_size < WS_NEEDED) {
        int n4 = out_size / 4;
        init_out_kernel<<<1563, 256, 0, stream>>>((const float4*)out_in, (float4*)out, n4);
        scatter_direct_kernel<<<2048, 256, 0, stream>>>(src, index, out);
        return;
    }

    char* ws = (char*)d_ws;
    int* blockcnt = (int*)(ws + BLKCNT_OFF);
    int* startg   = (int*)(ws + START_OFF);
    int* pb       = (int*)(ws + PB_OFF);
    int* offs     = (int*)(ws + OFFS_OFF);
    int* perm     = (int*)(ws + PERM_OFF);

    count_kernel<<<NBLK, 256, 0, stream>>>(index, blockcnt);
    scan_col_kernel<<<(NB * 64 + 255) / 256, 256, 0, stream>>>(blockcnt, startg);
    scan_bucket_kernel<<<1, 1024, 0, stream>>>(startg);
    partition_kernel<<<NBLK, 256, 0, stream>>>(index, blockcnt, startg, pb);
    finish_kernel<<<NB, 256, 0, stream>>>(pb, startg, offs, perm);
    gather_sum_kernel<<<(N_NODES + 3) / 4, 256, 0, stream>>>(
        (const float4*)src, perm, offs, (const float4*)out_in, (float4*)out);
}

// Round 12
// 77.217 us; speedup vs baseline: 5.1740x; 1.0311x over previous
//
#include <hip/hip_runtime.h>

#define N_EDGES 1600000
#define N_NODES 50000
#define D_FEAT  32

#define BSHIFT  6
#define NPB     64                                   // nodes per bucket
#define NB      ((N_NODES + NPB - 1) / NPB)          // 782 buckets
#define CHUNK   2048                                 // edges per partition block
#define NBLK    ((N_EDGES + CHUNK - 1) / CHUNK)      // 782 blocks
#define EPT     (CHUNK / 256)                        // 8 edges/thread
#define MAXB    6144                                 // lperm capacity (mean 2048 + 90 sigma)

// ---- workspace layout (bytes) ----
#define BLKCNT_OFF 0                                                       // int[NBLK*NB]
#define START_OFF  ((((size_t)NBLK * NB * 4 + 255) / 256) * 256)           // int[NB+1]
#define PB_OFF     (START_OFF + ((((size_t)(NB + 1) * 4 + 255) / 256) * 256)) // int[N_EDGES]
#define WS_NEEDED  (PB_OFF + (size_t)N_EDGES * 4)

// P1: per-block bucket histogram (LDS atomics only).
__global__ __launch_bounds__(256) void count_kernel(const int* __restrict__ index,
                                                    int* __restrict__ blockcnt) {
    __shared__ int lcnt[NB];
    int t = threadIdx.x;
    for (int k = t; k < NB; k += 256) lcnt[k] = 0;
    __syncthreads();
    int base = blockIdx.x * CHUNK;
    #pragma unroll
    for (int j = 0; j < EPT; ++j) {
        int e = base + j * 256 + t;
        if (e < N_EDGES) atomicAdd(&lcnt[index[e] >> BSHIFT], 1);
    }
    __syncthreads();
    for (int k = t; k < NB; k += 256)
        blockcnt[(size_t)blockIdx.x * NB + k] = lcnt[k];
}

// P2a: parallel column scan — one wave per bucket, shfl prefix over NBLK counts.
__global__ __launch_bounds__(256) void scan_col_kernel(int* __restrict__ blockcnt,
                                                       int* __restrict__ startg) {
    int wid  = (blockIdx.x * 256 + threadIdx.x) >> 6;
    int lane = threadIdx.x & 63;
    if (wid >= NB) return;
    int carry = 0;
    const int CH = (NBLK + 63) / 64;                 // 13 chunks
    for (int c = 0; c < CH; ++c) {
        int b = c * 64 + lane;
        int v = (b < NBLK) ? blockcnt[(size_t)b * NB + wid] : 0;
        int incl = v;
        #pragma unroll
        for (int d = 1; d < 64; d <<= 1) {
            int up = __shfl_up(incl, d, 64);
            if (lane >= d) incl += up;
        }
        if (b < NBLK) blockcnt[(size_t)b * NB + wid] = carry + incl - v;
        carry += __shfl(incl, 63, 64);
    }
    if (lane == 0) startg[wid] = carry;
}

// P2b: single-block exclusive scan of the bucket totals (in place).
__global__ __launch_bounds__(1024) void scan_bucket_kernel(int* __restrict__ startg) {
    __shared__ int part[1024];
    int t = threadIdx.x;
    int v = (t < NB) ? startg[t] : 0;
    part[t] = v;
    __syncthreads();
    int inc = v;
    for (int d = 1; d < 1024; d <<= 1) {
        int w = (t >= d) ? part[t - d] : 0;
        __syncthreads();
        inc += w;
        part[t] = inc;
        __syncthreads();
    }
    if (t < NB) startg[t] = inc - v;
    if (t == 0) startg[NB] = N_EDGES;
}

// P3: block-local multisplit -> bucket-ordered PACKED entries
// pb[i] = (edge<<6) | (node&63). CHUNK=2048: LDS ~27KB -> ~2x resident waves.
__global__ __launch_bounds__(256) void partition_kernel(const int* __restrict__ index,
                                                        const int* __restrict__ blockcnt,
                                                        const int* __restrict__ startg,
                                                        int* __restrict__ pb) {
    __shared__ int lcnt[NB];
    __shared__ int loff[NB];
    __shared__ int lbase[NB];
    __shared__ int scanp[256];
    __shared__ int2 stage[CHUNK];                  // 16 KB (node, edge)
    int t = threadIdx.x;
    int b = blockIdx.x;
    for (int k = t; k < NB; k += 256) lcnt[k] = 0;
    __syncthreads();
    int base = b * CHUNK;
    int nd[EPT], rk[EPT];
    #pragma unroll
    for (int j = 0; j < EPT; ++j) {
        int e = base + j * 256 + t;
        nd[j] = -1;
        if (e < N_EDGES) {
            nd[j] = index[e];
            rk[j] = atomicAdd(&lcnt[nd[j] >> BSHIFT], 1);
        }
    }
    __syncthreads();
    {   // exclusive scan of lcnt[0..NB)
        const int C = (NB + 255) / 256;            // 4
        int mybase = t * C;
        int s = 0;
        #pragma unroll
        for (int j = 0; j < C; ++j) {
            int i = mybase + j;
            if (i < NB) s += lcnt[i];
        }
        scanp[t] = s;
        __syncthreads();
        int inc = s;
        for (int d = 1; d < 256; d <<= 1) {
            int w = (t >= d) ? scanp[t - d] : 0;
            __syncthreads();
            inc += w;
            scanp[t] = inc;
            __syncthreads();
        }
        int run = inc - s;
        #pragma unroll
        for (int j = 0; j < C; ++j) {
            int i = mybase + j;
            if (i < NB) { loff[i] = run; run += lcnt[i]; }
        }
    }
    for (int k = t; k < NB; k += 256)
        lbase[k] = startg[k] + blockcnt[(size_t)b * NB + k];
    __syncthreads();
    #pragma unroll
    for (int j = 0; j < EPT; ++j) {
        if (nd[j] >= 0) {
            int e = base + j * 256 + t;
            int k = nd[j] >> BSHIFT;
            stage[loff[k] + rk[j]] = make_int2(nd[j], e);
        }
    }
    __syncthreads();
    int total = loff[NB - 1] + lcnt[NB - 1];
    for (int i = t; i < total; i += 256) {
        int2 ent = stage[i];
        int k = ent.x >> BSHIFT;
        pb[lbase[k] + (i - loff[k])] = (ent.y << BSHIFT) | (ent.x & (NPB - 1));
    }
}

// P4 (FUSED finish+gather): block k = bucket k. Build node-sorted local CSR
// in LDS (r10-proven logic), then 8 waves run the proven float4 4-deep
// gather reading lperm from LDS. perm/offs never touch global memory.
__global__ __launch_bounds__(512) void finish_gather_kernel(const int* __restrict__ pb,
                                                            const int* __restrict__ startg,
                                                            const float4* __restrict__ src4,
                                                            const float4* __restrict__ out_in4,
                                                            float4* __restrict__ out4) {
    __shared__ int lperm[MAXB];                    // 24 KB
    __shared__ int lcnt[NPB];
    __shared__ int lcur[NPB];
    __shared__ int loffs[NPB + 1];
    int t = threadIdx.x;
    int k = blockIdx.x;
    if (t < NPB) lcnt[t] = 0;
    __syncthreads();
    int s0 = startg[k], s1 = startg[k + 1];
    int cnt = s1 - s0;
    for (int i = t; i < cnt; i += 512)
        atomicAdd(&lcnt[pb[s0 + i] & (NPB - 1)], 1);
    __syncthreads();
    if (t == 0) {
        int run = 0;
        for (int n = 0; n < NPB; ++n) {
            loffs[n] = run;
            lcur[n] = run;
            run += lcnt[n];
        }
        loffs[NPB] = run;
    }
    __syncthreads();
    for (int i = t; i < cnt; i += 512) {
        int pv = pb[s0 + i];
        int r = atomicAdd(&lcur[pv & (NPB - 1)], 1);
        lperm[r] = pv >> BSHIFT;                   // edge id, node-sorted
    }
    __syncthreads();

    int wave = t >> 6, lane = t & 63;
    int slot = lane >> 3, f4 = lane & 7;
    for (int nl = wave; nl < NPB; nl += 8) {
        int gnode = k * NPB + nl;
        if (gnode >= N_NODES) break;
        int start = loffs[nl], end = loffs[nl + 1];
        float4 a0 = {0,0,0,0}, a1 = {0,0,0,0}, a2 = {0,0,0,0}, a3 = {0,0,0,0};
        int i = start + slot;
        for (; i + 24 < end; i += 32) {
            int e0 = lperm[i];
            int e1 = lperm[i + 8];
            int e2 = lperm[i + 16];
            int e3 = lperm[i + 24];
            float4 v0 = src4[(size_t)e0 * 8 + f4];
            float4 v1 = src4[(size_t)e1 * 8 + f4];
            float4 v2 = src4[(size_t)e2 * 8 + f4];
            float4 v3 = src4[(size_t)e3 * 8 + f4];
            a0.x += v0.x; a0.y += v0.y; a0.z += v0.z; a0.w += v0.w;
            a1.x += v1.x; a1.y += v1.y; a1.z += v1.z; a1.w += v1.w;
            a2.x += v2.x; a2.y += v2.y; a2.z += v2.z; a2.w += v2.w;
            a3.x += v3.x; a3.y += v3.y; a3.z += v3.z; a3.w += v3.w;
        }
        for (; i < end; i += 8) {
            int e0 = lperm[i];
            float4 v0 = src4[(size_t)e0 * 8 + f4];
            a0.x += v0.x; a0.y += v0.y; a0.z += v0.z; a0.w += v0.w;
        }
        a0.x += a1.x + a2.x + a3.x;
        a0.y += a1.y + a2.y + a3.y;
        a0.z += a1.z + a2.z + a3.z;
        a0.w += a1.w + a2.w + a3.w;
        for (int m = 8; m <= 32; m <<= 1) {
            a0.x += __shfl_xor(a0.x, m, 64);
            a0.y += __shfl_xor(a0.y, m, 64);
            a0.z += __shfl_xor(a0.z, m, 64);
            a0.w += __shfl_xor(a0.w, m, 64);
        }
        if (slot == 0) {
            size_t o = (size_t)gnode * 8 + f4;
            float4 bo = out_in4[o];
            bo.x += a0.x; bo.y += a0.y; bo.z += a0.z; bo.w += a0.w;
            out4[o] = bo;
        }
    }
}

// ---- fallback: round-8 proven direct atomic path (171 us) ----
__global__ void init_out_kernel(const float4* __restrict__ out_in,
                                float4* __restrict__ out, int n4) {
    int i = blockIdx.x * blockDim.x + threadIdx.x;
    int stride = gridDim.x * blockDim.x;
    for (; i < n4; i += stride) out[i] = out_in[i];
}
__global__ void scatter_direct_kernel(const float* __restrict__ src,
                                      const int* __restrict__ index,
                                      float* __restrict__ out) {
    const long total = (long)N_EDGES * D_FEAT;
    long i = (long)blockIdx.x * blockDim.x + threadIdx.x;
    const long stride = (long)gridDim.x * blockDim.x;
    for (; i < total; i += stride) {
        int e = (int)(i >> 5);
        int f = (int)(i & 31);
        float v = src[i];
        int node = index[e];
        atomicAdd(&out[(size_t)node * D_FEAT + f], v);
    }
}

extern "C" void kernel_launch(void* const* d_in, const int* in_sizes, int n_in,
                              void* d_out, int out_size, void* d_ws, size_t ws_size,
                              hipStream_t stream) {
    const float* src    = (const float*)d_in[0];
    const int*   index  = (const int*)d_in[1];
    const float* out_in = (const float*)d_in[2];
    float* out          = (float*)d_out;

    if (ws_size < WS_NEEDED) {
        int n4 = out_size / 4;
        init_out_kernel<<<1563, 256, 0, stream>>>((const float4*)out_in, (float4*)out, n4);
        scatter_direct_kernel<<<2048, 256, 0, stream>>>(src, index, out);
        return;
    }

    char* ws = (char*)d_ws;
    int* blockcnt = (int*)(ws + BLKCNT_OFF);
    int* startg   = (int*)(ws + START_OFF);
    int* pb       = (int*)(ws + PB_OFF);

    count_kernel<<<NBLK, 256, 0, stream>>>(index, blockcnt);
    scan_col_kernel<<<(NB * 64 + 255) / 256, 256, 0, stream>>>(blockcnt, startg);
    scan_bucket_kernel<<<1, 1024, 0, stream>>>(startg);
    partition_kernel<<<NBLK, 256, 0, stream>>>(index, blockcnt, startg, pb);
    finish_gather_kernel<<<NB, 512, 0, stream>>>(pb, startg, (const float4*)src,
                                                 (const float4*)out_in, (float4*)out);
}

// Round 13
// 68.789 us; speedup vs baseline: 5.8079x; 1.1225x over previous
//
#include <hip/hip_runtime.h>

#define N_EDGES 1600000
#define N_NODES 50000
#define D_FEAT  32

#define BSHIFT  6
#define NPB     64                                   // nodes per bucket
#define NB      ((N_NODES + NPB - 1) / NPB)          // 782 buckets
#define CHUNK   4096                                 // edges per count/partition block
#define NBLK    ((N_EDGES + CHUNK - 1) / CHUNK)      // 391 blocks
#define EPT     (CHUNK / 256)                        // 16 edges/thread
#define EPT4    (EPT / 4)                            // 4 int4/thread
#define MAXB    6144                                 // lperm capacity (mean 2048 + 90 sigma)

// ---- workspace layout (bytes) ----
#define BLKCNT_OFF 0                                                       // int[NBLK*NB]
#define START_OFF  ((((size_t)NBLK * NB * 4 + 255) / 256) * 256)           // int[NB+1]
#define PB_OFF     (START_OFF + ((((size_t)(NB + 1) * 4 + 255) / 256) * 256)) // int[N_EDGES]
#define WS_NEEDED  (PB_OFF + (size_t)N_EDGES * 4)

// P1: per-block bucket histogram, int4 index reads, LDS atomics only.
__global__ __launch_bounds__(256) void count_kernel(const int4* __restrict__ index4,
                                                    int* __restrict__ blockcnt) {
    __shared__ int lcnt[NB];
    int t = threadIdx.x;
    for (int k = t; k < NB; k += 256) lcnt[k] = 0;
    __syncthreads();
    int base4 = blockIdx.x * (CHUNK / 4);
    #pragma unroll
    for (int j = 0; j < EPT4; ++j) {
        int e4 = base4 + j * 256 + t;
        if (e4 < N_EDGES / 4) {
            int4 v = index4[e4];
            atomicAdd(&lcnt[v.x >> BSHIFT], 1);
            atomicAdd(&lcnt[v.y >> BSHIFT], 1);
            atomicAdd(&lcnt[v.z >> BSHIFT], 1);
            atomicAdd(&lcnt[v.w >> BSHIFT], 1);
        }
    }
    __syncthreads();
    for (int k = t; k < NB; k += 256)
        blockcnt[(size_t)blockIdx.x * NB + k] = lcnt[k];
}

// P2a: parallel column scan — one wave per bucket, shfl prefix over NBLK counts.
__global__ __launch_bounds__(256) void scan_col_kernel(int* __restrict__ blockcnt,
                                                       int* __restrict__ startg) {
    int wid  = (blockIdx.x * 256 + threadIdx.x) >> 6;
    int lane = threadIdx.x & 63;
    if (wid >= NB) return;
    int carry = 0;
    const int CH = (NBLK + 63) / 64;                 // 7 chunks
    for (int c = 0; c < CH; ++c) {
        int b = c * 64 + lane;
        int v = (b < NBLK) ? blockcnt[(size_t)b * NB + wid] : 0;
        int incl = v;
        #pragma unroll
        for (int d = 1; d < 64; d <<= 1) {
            int up = __shfl_up(incl, d, 64);
            if (lane >= d) incl += up;
        }
        if (b < NBLK) blockcnt[(size_t)b * NB + wid] = carry + incl - v;
        carry += __shfl(incl, 63, 64);
    }
    if (lane == 0) startg[wid] = carry;
}

// P2b: single-block exclusive scan of the bucket totals (in place).
__global__ __launch_bounds__(1024) void scan_bucket_kernel(int* __restrict__ startg) {
    __shared__ int part[1024];
    int t = threadIdx.x;
    int v = (t < NB) ? startg[t] : 0;
    part[t] = v;
    __syncthreads();
    int inc = v;
    for (int d = 1; d < 1024; d <<= 1) {
        int w = (t >= d) ? part[t - d] : 0;
        __syncthreads();
        inc += w;
        part[t] = inc;
        __syncthreads();
    }
    if (t < NB) startg[t] = inc - v;
    if (t == 0) startg[NB] = N_EDGES;
}

// P3: block-local multisplit -> bucket-ordered PACKED entries
// pb[i] = (edge<<6) | (node&63). int4 index reads; int2 LDS stage.
__global__ __launch_bounds__(256) void partition_kernel(const int4* __restrict__ index4,
                                                        const int* __restrict__ blockcnt,
                                                        const int* __restrict__ startg,
                                                        int* __restrict__ pb) {
    __shared__ int lcnt[NB];
    __shared__ int loff[NB];
    __shared__ int lbase[NB];
    __shared__ int scanp[256];
    __shared__ int2 stage[CHUNK];                  // 32 KB (node, edge)
    int t = threadIdx.x;
    int b = blockIdx.x;
    for (int k = t; k < NB; k += 256) lcnt[k] = 0;
    __syncthreads();
    int base4 = b * (CHUNK / 4);
    int nd[EPT], rk[EPT];
    #pragma unroll
    for (int j = 0; j < EPT4; ++j) {
        int e4 = base4 + j * 256 + t;
        if (e4 < N_EDGES / 4) {
            int4 v = index4[e4];
            nd[j * 4 + 0] = v.x; rk[j * 4 + 0] = atomicAdd(&lcnt[v.x >> BSHIFT], 1);
            nd[j * 4 + 1] = v.y; rk[j * 4 + 1] = atomicAdd(&lcnt[v.y >> BSHIFT], 1);
            nd[j * 4 + 2] = v.z; rk[j * 4 + 2] = atomicAdd(&lcnt[v.z >> BSHIFT], 1);
            nd[j * 4 + 3] = v.w; rk[j * 4 + 3] = atomicAdd(&lcnt[v.w >> BSHIFT], 1);
        } else {
            nd[j * 4 + 0] = nd[j * 4 + 1] = nd[j * 4 + 2] = nd[j * 4 + 3] = -1;
        }
    }
    __syncthreads();
    {   // exclusive scan of lcnt[0..NB)
        const int C = (NB + 255) / 256;            // 4
        int mybase = t * C;
        int s = 0;
        #pragma unroll
        for (int j = 0; j < C; ++j) {
            int i = mybase + j;
            if (i < NB) s += lcnt[i];
        }
        scanp[t] = s;
        __syncthreads();
        int inc = s;
        for (int d = 1; d < 256; d <<= 1) {
            int w = (t >= d) ? scanp[t - d] : 0;
            __syncthreads();
            inc += w;
            scanp[t] = inc;
            __syncthreads();
        }
        int run = inc - s;
        #pragma unroll
        for (int j = 0; j < C; ++j) {
            int i = mybase + j;
            if (i < NB) { loff[i] = run; run += lcnt[i]; }
        }
    }
    for (int k = t; k < NB; k += 256)
        lbase[k] = startg[k] + blockcnt[(size_t)b * NB + k];
    __syncthreads();
    #pragma unroll
    for (int j = 0; j < EPT; ++j) {
        if (nd[j] >= 0) {
            int e4 = base4 + (j >> 2) * 256 + t;
            int e = e4 * 4 + (j & 3);
            int k = nd[j] >> BSHIFT;
            stage[loff[k] + rk[j]] = make_int2(nd[j], e);
        }
    }
    __syncthreads();
    int total = loff[NB - 1] + lcnt[NB - 1];
    for (int i = t; i < total; i += 256) {
        int2 ent = stage[i];
        int k = ent.x >> BSHIFT;
        pb[lbase[k] + (i - loff[k])] = (ent.y << BSHIFT) | (ent.x & (NPB - 1));
    }
}

// P4 (fused finish+gather): block k = bucket k. Build node-sorted local CSR
// in LDS, then 8 waves run the proven float4 4-deep gather from lperm.
// Serial t==0 prefix scan replaced by a wave-0 shfl scan.
__global__ __launch_bounds__(512) void finish_gather_kernel(const int* __restrict__ pb,
                                                            const int* __restrict__ startg,
                                                            const float4* __restrict__ src4,
                                                            const float4* __restrict__ out_in4,
                                                            float4* __restrict__ out4) {
    __shared__ int lperm[MAXB];                    // 24 KB
    __shared__ int lcnt[NPB];
    __shared__ int lcur[NPB];
    __shared__ int loffs[NPB + 1];
    int t = threadIdx.x;
    int k = blockIdx.x;
    if (t < NPB) lcnt[t] = 0;
    __syncthreads();
    int s0 = startg[k], s1 = startg[k + 1];
    int cnt = s1 - s0;
    for (int i = t; i < cnt; i += 512)
        atomicAdd(&lcnt[pb[s0 + i] & (NPB - 1)], 1);
    __syncthreads();
    if (t < NPB) {                                 // wave-0 shfl prefix scan
        int v = lcnt[t];
        int inc = v;
        #pragma unroll
        for (int d = 1; d < 64; d <<= 1) {
            int up = __shfl_up(inc, d, 64);
            if (t >= d) inc += up;
        }
        loffs[t] = inc - v;
        lcur[t]  = inc - v;
        if (t == NPB - 1) loffs[NPB] = inc;
    }
    __syncthreads();
    for (int i = t; i < cnt; i += 512) {
        int pv = pb[s0 + i];
        int r = atomicAdd(&lcur[pv & (NPB - 1)], 1);
        lperm[r] = pv >> BSHIFT;                   // edge id, node-sorted
    }
    __syncthreads();

    int wave = t >> 6, lane = t & 63;
    int slot = lane >> 3, f4 = lane & 7;
    for (int nl = wave; nl < NPB; nl += 8) {
        int gnode = k * NPB + nl;
        if (gnode >= N_NODES) break;
        int start = loffs[nl], end = loffs[nl + 1];
        float4 a0 = {0,0,0,0}, a1 = {0,0,0,0}, a2 = {0,0,0,0}, a3 = {0,0,0,0};
        int i = start + slot;
        for (; i + 24 < end; i += 32) {
            int e0 = lperm[i];
            int e1 = lperm[i + 8];
            int e2 = lperm[i + 16];
            int e3 = lperm[i + 24];
            float4 v0 = src4[(size_t)e0 * 8 + f4];
            float4 v1 = src4[(size_t)e1 * 8 + f4];
            float4 v2 = src4[(size_t)e2 * 8 + f4];
            float4 v3 = src4[(size_t)e3 * 8 + f4];
            a0.x += v0.x; a0.y += v0.y; a0.z += v0.z; a0.w += v0.w;
            a1.x += v1.x; a1.y += v1.y; a1.z += v1.z; a1.w += v1.w;
            a2.x += v2.x; a2.y += v2.y; a2.z += v2.z; a2.w += v2.w;
            a3.x += v3.x; a3.y += v3.y; a3.z += v3.z; a3.w += v3.w;
        }
        for (; i < end; i += 8) {
            int e0 = lperm[i];
            float4 v0 = src4[(size_t)e0 * 8 + f4];
            a0.x += v0.x; a0.y += v0.y; a0.z += v0.z; a0.w += v0.w;
        }
        a0.x += a1.x + a2.x + a3.x;
        a0.y += a1.y + a2.y + a3.y;
        a0.z += a1.z + a2.z + a3.z;
        a0.w += a1.w + a2.w + a3.w;
        for (int m = 8; m <= 32; m <<= 1) {
            a0.x += __shfl_xor(a0.x, m, 64);
            a0.y += __shfl_xor(a0.y, m, 64);
            a0.z += __shfl_xor(a0.z, m, 64);
            a0.w += __shfl_xor(a0.w, m, 64);
        }
        if (slot == 0) {
            size_t o = (size_t)gnode * 8 + f4;
            float4 bo = out_in4[o];
            bo.x += a0.x; bo.y += a0.y; bo.z += a0.z; bo.w += a0.w;
            out4[o] = bo;
        }
    }
}

// ---- fallback: round-8 proven direct atomic path (171 us) ----
__global__ void init_out_kernel(const float4* __restrict__ out_in,
                                float4* __restrict__ out, int n4) {
    int i = blockIdx.x * blockDim.x + threadIdx.x;
    int stride = gridDim.x * blockDim.x;
    for (; i < n4; i += stride) out[i] = out_in[i];
}
__global__ void scatter_direct_kernel(const float* __restrict__ src,
                                      const int* __restrict__ index,
                                      float* __restrict__ out) {
    const long total = (long)N_EDGES * D_FEAT;
    long i = (long)blockIdx.x * blockDim.x + threadIdx.x;
    const long stride = (long)gridDim.x * blockDim.x;
    for (; i < total; i += stride) {
        int e = (int)(i >> 5);
        int f = (int)(i & 31);
        float v = src[i];
        int node = index[e];
        atomicAdd(&out[(size_t)node * D_FEAT + f], v);
    }
}

extern "C" void kernel_launch(void* const* d_in, const int* in_sizes, int n_in,
                              void* d_out, int out_size, void* d_ws, size_t ws_size,
                              hipStream_t stream) {
    const float* src    = (const float*)d_in[0];
    const int*   index  = (const int*)d_in[1];
    const float* out_in = (const float*)d_in[2];
    float* out          = (float*)d_out;

    if (ws_size < WS_NEEDED) {
        int n4 = out_size / 4;
        init_out_kernel<<<1563, 256, 0, stream>>>((const float4*)out_in, (float4*)out, n4);
        scatter_direct_kernel<<<2048, 256, 0, stream>>>(src, index, out);
        return;
    }

    char* ws = (char*)d_ws;
    int* blockcnt = (int*)(ws + BLKCNT_OFF);
    int* startg   = (int*)(ws + START_OFF);
    int* pb       = (int*)(ws + PB_OFF);

    count_kernel<<<NBLK, 256, 0, stream>>>((const int4*)index, blockcnt);
    scan_col_kernel<<<(NB * 64 + 255) / 256, 256, 0, stream>>>(blockcnt, startg);
    scan_bucket_kernel<<<1, 1024, 0, stream>>>(startg);
    partition_kernel<<<NBLK, 256, 0, stream>>>((const int4*)index, blockcnt, startg, pb);
    finish_gather_kernel<<<NB, 512, 0, stream>>>(pb, startg, (const float4*)src,
                                                 (const float4*)out_in, (float4*)out);
}